// Round 1
// baseline (27115.921 us; speedup 1.0000x reference)
//
#include <hip/hip_runtime.h>
#include <hip/hip_bf16.h>
#include <hip/hip_cooperative_groups.h>

namespace cg = cooperative_groups;

#define Bdim 256
#define Tdim 256
#define Idim 256
#define Hdim 1024
#define KDIM 1280   // I + H
#define NP   4096   // 4*H, gate-interleaved: n' = 4*hu + gate

typedef __attribute__((ext_vector_type(8)))  short short8;
typedef __attribute__((ext_vector_type(16))) float f32x16;

__device__ __forceinline__ short f2bf(float f) {
  unsigned u = __builtin_bit_cast(unsigned, f);
  unsigned r = (u + 0x7FFFu + ((u >> 16) & 1u)) >> 16;   // RNE
  return (short)r;
}
__device__ __forceinline__ float bf2f(short s) {
  unsigned u = ((unsigned)(unsigned short)s) << 16;
  return __builtin_bit_cast(float, u);
}

// ---------------- setup: Wt[n'][k] = bf16(W[k][(n'&3)*H + (n'>>2)]) ----------------
__global__ void setup_wt_kernel(const float* __restrict__ Wx,
                                const float* __restrict__ Wh,
                                short* __restrict__ Wt) {
  __shared__ float tile[64 * 65];
  const int nb = blockIdx.x, kb = blockIdx.y;
  const int tid = threadIdx.x;
#pragma unroll
  for (int i = 0; i < 16; ++i) {
    int idx = i * 256 + tid;
    int kr = idx >> 6, nc = idx & 63;
    int kglob = kb * 64 + kr;
    int np = nb * 64 + nc;
    int col = ((np & 3) << 10) | (np >> 2);
    float v = (kglob < Idim) ? Wx[(size_t)kglob * NP + col]
                             : Wh[(size_t)(kglob - Idim) * NP + col];
    tile[kr * 65 + nc] = v;
  }
  __syncthreads();
#pragma unroll
  for (int i = 0; i < 16; ++i) {
    int idx = i * 256 + tid;
    int nr = idx >> 6, kc = idx & 63;
    Wt[(size_t)(nb * 64 + nr) * KDIM + kb * 64 + kc] = f2bf(tile[kc * 65 + nr]);
  }
}

// ---------------- setup: state init + bias reorder ----------------
__global__ void setup_state_kernel(const float* __restrict__ h0,
                                   const float* __restrict__ c0,
                                   const float* __restrict__ b,
                                   short* __restrict__ Uh0,
                                   float* __restrict__ c_state,
                                   float* __restrict__ bp) {
  int idx = blockIdx.x * 256 + threadIdx.x;
  if (blockIdx.x < 1024) {          // B*H = 262144 state elems
    Uh0[idx] = f2bf(h0[idx]);
    c_state[idx] = c0[idx];
  } else {                          // 4096 bias elems
    int j = idx - 1024 * 256;
    bp[j] = b[((j & 3) << 10) | (j >> 2)];
  }
}

// ---------------- persistent fused LSTM ----------------
// Grid 256 blocks x 512 threads (8 waves), cooperative launch, 1 block/CU.
// block = (m = blockIdx&7 batch-tile of 32 rows, ng = blockIdx>>3 hu-group of 32).
//   (m = low 3 bits so each m-group of 32 blocks lands on one XCD under
//    round-robin dispatch -> h-state handoff stays in local L2.)
// wave = (ntl = wave&3: 32-wide n' tile, kh = wave>>2: 640-wide K half).
// Weights: 32x640 bf16 slice per wave held in 40 x short8 = 160 VGPRs for the
// whole sequence (read from HBM once). Per step: stage A=[x_t|h] (32x1280 bf16)
// into XOR-swizzled LDS, 40 MFMAs/wave from LDS+regs, 2-way K-reduce via LDS,
// fused LSTM epilogue, grid sync.
__global__ __launch_bounds__(512, 2) void lstm_persistent(
    const float* __restrict__ xin,    // (B,T,I) fp32
    const short* __restrict__ Wt,     // (NP, KDIM) bf16
    const float* __restrict__ bp,     // (NP) fp32 reordered
    short* __restrict__ Uh0,          // (B,H) bf16 h state buf 0
    short* __restrict__ Uh1,          // (B,H) bf16 h state buf 1
    float* __restrict__ out,          // (B,T,H) fp32
    float* __restrict__ c_state,      // (B,H) fp32 (aliases cN output)
    float* __restrict__ hN) {         // (B,H) fp32 final h
  __shared__ __align__(16) short As[32 * KDIM];       // 80 KB, swizzled
  __shared__ __align__(16) float Gred[2][32][132];    // 33.8 KB (padded rows)

  const int tid  = threadIdx.x;
  const int lane = tid & 63;
  const int wave = tid >> 6;        // 0..7
  const int ntl  = wave & 3;        // n-tile within block
  const int kh   = wave >> 2;       // K half (0: k<640, 1: k>=640)
  const int m    = blockIdx.x & 7;  // batch-tile (XCD-local group)
  const int ng   = blockIdx.x >> 3; // 0..31 hu-group
  const int bm0  = m * 32;
  const int n0   = ng * 128 + ntl * 32;

  // ---- one-time: weights into registers (40 x short8 = 160 VGPR) ----
  short8 Wreg[40];
  {
    const short* wr = Wt + (size_t)(n0 + (lane & 31)) * KDIM + kh * 640 + ((lane >> 5) << 3);
#pragma unroll
    for (int ks = 0; ks < 40; ++ks) Wreg[ks] = *(const short8*)(wr + ks * 16);
  }

  // epilogue constants: this thread owns cells (row = tid>>5 (+16), hul = tid&31)
  const int hul = tid & 31;
  const float4 bb = ((const float4*)bp)[ng * 32 + hul];

  // A-fragment swizzled-read pieces (XOR swizzle: byte ^= (row&15)<<4;
  // row stride 2560 B == 0 mod 512 so the XOR stays inside the row)
  const int arow  = lane & 31;
  const int rbase = arow * 2560 + kh * 1280 + ((lane >> 5) << 4);
  const int rxor  = (arow & 15) << 4;

  cg::grid_group grid = cg::this_grid();

  for (int t = 0; t < Tdim; ++t) {
    const short* UhR = (t & 1) ? Uh1 : Uh0;
    short* UhW = (t & 1) ? Uh0 : Uh1;

    // ---- stage A = [x_t (fp32->bf16) | h (bf16)] into LDS ----
#pragma unroll
    for (int i = 0; i < 2; ++i) {          // x part: 1024 short8 units
      int unit = i * 512 + tid;
      int row = unit >> 5, c8 = (unit & 31) << 3;
      const float* p = xin + (size_t)(bm0 + row) * (Tdim * Idim) + (size_t)t * Idim + c8;
      float4 a = *(const float4*)p, b4 = *(const float4*)(p + 4);
      short8 v;
      v[0] = f2bf(a.x);  v[1] = f2bf(a.y);  v[2] = f2bf(a.z);  v[3] = f2bf(a.w);
      v[4] = f2bf(b4.x); v[5] = f2bf(b4.y); v[6] = f2bf(b4.z); v[7] = f2bf(b4.w);
      *(short8*)((char*)As + (((row * 2560) + (c8 << 1)) ^ ((row & 15) << 4))) = v;
    }
#pragma unroll
    for (int i = 0; i < 8; ++i) {          // h part: 4096 short8 units
      int unit = i * 512 + tid;
      int row = unit >> 7, c8 = (unit & 127) << 3;
      short8 v = *(const short8*)(UhR + (size_t)(bm0 + row) * Hdim + c8);
      if (t > 0 && c8 == 0) {
        // oscillator state update on h cols 0,1 (transient, gate-input only)
        float x0 = bf2f(v[0]), x1 = bf2f(v[1]);
        v[0] = f2bf(x0 + 0.05f * (1.5f * x0 + (1.0f / 1.5f) * x1));
        v[1] = f2bf(x1 - 0.05f * 1.5f * x0);
      }
      *(short8*)((char*)As + (((row * 2560) + ((256 + c8) << 1)) ^ ((row & 15) << 4))) = v;
    }
    __syncthreads();

    // ---- MFMA: acc(32x32) += A[32 x 640-half] * W[640-half x 32] ----
    f32x16 acc;
#pragma unroll
    for (int i = 0; i < 16; ++i) acc[i] = 0.f;
#pragma unroll
    for (int ks = 0; ks < 40; ++ks) {
      short8 a = *(const short8*)((char*)As + ((rbase + ks * 32) ^ rxor));
      acc = __builtin_amdgcn_mfma_f32_32x32x16_bf16(a, Wreg[ks], acc, 0, 0, 0);
    }

    // ---- K-half partials to LDS (prev epilogue's Gred reads were fenced
    //      off by last step's grid.sync) ----
    {
      const int col = lane & 31, half = lane >> 5;
#pragma unroll
      for (int r = 0; r < 16; ++r) {
        int rl = (r & 3) + 8 * (r >> 2) + 4 * half;
        Gred[kh][rl][ntl * 32 + col] = acc[r];
      }
    }
    __syncthreads();

    // ---- fused LSTM epilogue: 1024 (batch,hu) cells, 2 per thread ----
#pragma unroll
    for (int i = 0; i < 2; ++i) {
      int row = (tid >> 5) + i * 16;
      float4 g0 = *(const float4*)&Gred[0][row][hul * 4];
      float4 g1 = *(const float4*)&Gred[1][row][hul * 4];
      float gx = g0.x + g1.x + bb.x;
      float gy = g0.y + g1.y + bb.y;
      float gz = g0.z + g1.z + bb.z;
      float gw = g0.w + g1.w + bb.w;
      float iv = 1.0f / (1.0f + __expf(-gx));
      float fv = 1.0f / (1.0f + __expf(-gy));
      float gg = 2.0f / (1.0f + __expf(-2.0f * gz)) - 1.0f;  // tanh
      float ov = 1.0f / (1.0f + __expf(-gw));
      int bm = bm0 + row;
      int hu = ng * 32 + hul;
      size_t cidx = (size_t)bm * Hdim + hu;
      float cn = fv * c_state[cidx] + iv * gg;
      c_state[cidx] = cn;
      float hv = ov * (2.0f / (1.0f + __expf(-2.0f * cn)) - 1.0f);
      out[(size_t)bm * (Tdim * Hdim) + (size_t)t * Hdim + hu] = hv;
      UhW[cidx] = f2bf(hv);
      if (t == Tdim - 1) hN[cidx] = hv;
    }

    __threadfence();   // release h/c writes to device scope
    grid.sync();
    __threadfence();   // acquire other XCDs' h writes before next staging
  }
}

extern "C" void kernel_launch(void* const* d_in, const int* in_sizes, int n_in,
                              void* d_out, int out_size, void* d_ws, size_t ws_size,
                              hipStream_t stream) {
  const float* xin = (const float*)d_in[0];
  const float* h0  = (const float*)d_in[1];
  const float* c0  = (const float*)d_in[2];
  const float* Wx  = (const float*)d_in[3];
  const float* Wh  = (const float*)d_in[4];
  const float* b   = (const float*)d_in[5];
  float* out = (float*)d_out;

  // workspace layout (~11.6 MB): Wt | Uh0 | Uh1 | bp
  char* ws = (char*)d_ws;
  short* Wt  = (short*)ws;                                   // 4096*1280*2 = 10485760
  short* Uh0 = (short*)(ws + 10485760);                      // 524288
  short* Uh1 = (short*)(ws + 10485760 + 524288);             // 524288
  float* bp  = (float*)(ws + 10485760 + 1048576);            // 16384

  float* hN      = out + (size_t)Bdim * Tdim * Hdim;
  float* c_state = hN + (size_t)Bdim * Hdim;   // cN region doubles as running c

  setup_wt_kernel<<<dim3(64, 20), 256, 0, stream>>>(Wx, Wh, Wt);
  setup_state_kernel<<<1040, 256, 0, stream>>>(h0, c0, b, Uh0, c_state, bp);

  void* args[] = {(void*)&xin, (void*)&Wt, (void*)&bp, (void*)&Uh0, (void*)&Uh1,
                  (void*)&out, (void*)&c_state, (void*)&hN};
  hipLaunchCooperativeKernel((const void*)lstm_persistent, dim3(256), dim3(512),
                             args, 0, stream);
}

// Round 3
// 2220.369 us; speedup vs baseline: 12.2123x; 12.2123x over previous
//
#include <hip/hip_runtime.h>
#include <hip/hip_bf16.h>

#define Bdim 256
#define Tdim 256
#define Idim 256
#define Hdim 1024
#define KDIM 1280   // I + H
#define NP   4096   // 4*H, gate-interleaved: n' = 4*hu + gate

typedef __attribute__((ext_vector_type(8)))  short short8;
typedef __attribute__((ext_vector_type(4)))  short short4v;
typedef __attribute__((ext_vector_type(16))) float f32x16;
typedef unsigned long long u64;

__device__ __forceinline__ short f2bf(float f) {
  unsigned u = __builtin_bit_cast(unsigned, f);
  unsigned r = (u + 0x7FFFu + ((u >> 16) & 1u)) >> 16;   // RNE
  return (short)r;
}
__device__ __forceinline__ float bf2f(short s) {
  unsigned u = ((unsigned)(unsigned short)s) << 16;
  return __builtin_bit_cast(float, u);
}

// ---------------- setup: Wt[n'][k] = bf16(W[k][(n'&3)*H + (n'>>2)]) ----------------
__global__ void setup_wt_kernel(const float* __restrict__ Wx,
                                const float* __restrict__ Wh,
                                short* __restrict__ Wt) {
  __shared__ float tile[64 * 65];
  const int nb = blockIdx.x, kb = blockIdx.y;
  const int tid = threadIdx.x;
#pragma unroll
  for (int i = 0; i < 16; ++i) {
    int idx = i * 256 + tid;
    int kr = idx >> 6, nc = idx & 63;
    int kglob = kb * 64 + kr;
    int np = nb * 64 + nc;
    int col = ((np & 3) << 10) | (np >> 2);
    float v = (kglob < Idim) ? Wx[(size_t)kglob * NP + col]
                             : Wh[(size_t)(kglob - Idim) * NP + col];
    tile[kr * 65 + nc] = v;
  }
  __syncthreads();
#pragma unroll
  for (int i = 0; i < 16; ++i) {
    int idx = i * 256 + tid;
    int nr = idx >> 6, kc = idx & 63;
    Wt[(size_t)(nb * 64 + nr) * KDIM + kb * 64 + kc] = f2bf(tile[kc * 65 + nr]);
  }
}

// ---------------- setup: state init + bias reorder + barrier zero ----------------
__global__ void setup_state_kernel(const float* __restrict__ h0,
                                   const float* __restrict__ c0,
                                   const float* __restrict__ b,
                                   short* __restrict__ Uh0,
                                   float* __restrict__ c_state,
                                   float* __restrict__ bp,
                                   unsigned* __restrict__ bar) {
  if (blockIdx.x == 1041) {
    if (threadIdx.x < 256) bar[threadIdx.x] = 0u;
    return;
  }
  int idx = blockIdx.x * 256 + threadIdx.x;
  if (blockIdx.x < 1024) {          // B*H = 262144 state elems
    Uh0[idx] = f2bf(h0[idx]);
    c_state[idx] = c0[idx];
  } else if (blockIdx.x < 1040) {
    int j = idx - 1024 * 256;
    if (j < NP) bp[j] = b[((j & 3) << 10) | (j >> 2)];
  }
}

// ---------------- persistent fused LSTM ----------------
// 256 blocks x 512 threads (8 waves), cooperative launch (co-residency only —
// no grid.sync, no threadfence: L2 stays warm with the weights).
// block = (m = blockIdx&7 batch-tile of 32 rows, ng = blockIdx>>3 hu-group).
// wave = (ntl = wave&3 : 32-wide n' tile, kh = wave>>2 : 640-wide K half).
// Weights: 40 x short8 = 160 VGPRs/wave, loaded once, pinned via asm keep-alive.
// Cross-block data (h state, barrier flags) ONLY via relaxed agent-scope HIP
// atomics (compiler emits the coherent sc0/sc1 path). Ordering: per-wave
// s_waitcnt vmcnt(0) + __syncthreads before setting the flag.
__global__ __launch_bounds__(512) __attribute__((amdgpu_waves_per_eu(2, 2)))
void lstm_persistent(
    const float* __restrict__ xin,    // (B,T,I) fp32
    const short* __restrict__ Wt,     // (NP, KDIM) bf16
    const float* __restrict__ bp,     // (NP) fp32 reordered
    short* __restrict__ Uh0,          // (B,H) bf16 h state buf 0
    short* __restrict__ Uh1,          // (B,H) bf16 h state buf 1
    float* __restrict__ out,          // (B,T,H) fp32
    float* __restrict__ c_state,      // (B,H) fp32 (aliases cN output)
    float* __restrict__ hN,           // (B,H) fp32 final h
    unsigned* __restrict__ bar) {     // flags: bar[m*32 + ng] = steps completed
  __shared__ __align__(16) short As[32 * KDIM];       // 80 KB, swizzled
  __shared__ __align__(16) float Gred[2][32][132];    // 33.8 KB (padded rows)

  const int tid  = threadIdx.x;
  const int lane = tid & 63;
  const int wave = tid >> 6;        // 0..7
  const int ntl  = wave & 3;        // n-tile within block
  const int kh   = wave >> 2;       // K half (0: k<640, 1: k>=640)
  const int m    = blockIdx.x & 7;  // batch-tile
  const int ng   = blockIdx.x >> 3; // 0..31 hu-group
  const int bm0  = m * 32;
  const int n0   = ng * 128 + ntl * 32;

  // ---- one-time: weights into registers (40 x short8 = 160 VGPR) ----
  short8 Wreg[40];
  {
    const short* wr = Wt + (size_t)(n0 + (lane & 31)) * KDIM + kh * 640 + ((lane >> 5) << 3);
#pragma unroll
    for (int ks = 0; ks < 40; ++ks) Wreg[ks] = *(const short8*)(wr + ks * 16);
  }
#pragma unroll
  for (int ks = 0; ks < 40; ++ks) asm volatile("" : "+v"(Wreg[ks]));

  // A-fragment swizzled-read pieces
  const int arow  = lane & 31;
  const int rbase = arow * 2560 + kh * 1280 + ((lane >> 5) << 4);
  const int rxor  = (arow & 15) << 4;

  // staging geometry (h part): thread owns rows row0+4i, fixed col c8
  const int row0 = tid >> 7;            // 0..3
  const int c8   = (tid & 127) << 3;    // 0..1016

  // epilogue geometry: thread owns (row erow, hu pair 2ep, 2ep+1)
  const int erow = tid >> 4;            // 0..31
  const int ep   = tid & 15;            // 0..15
  const float4 bb0 = ((const float4*)bp)[ng * 32 + 2 * ep];
  const float4 bb1 = ((const float4*)bp)[ng * 32 + 2 * ep + 1];

  unsigned* flags = bar + m * 32;

  for (int t = 0; t < Tdim; ++t) {
    const short* UhR = (t & 1) ? Uh1 : Uh0;
    short* UhW = (t & 1) ? Uh0 : Uh1;

    // ---- stage A = [x_t (fp32->bf16) | h (coherent bf16)] into LDS ----
#pragma unroll
    for (int i = 0; i < 2; ++i) {          // x part: 1024 short8 units
      int unit = i * 512 + tid;
      int row = unit >> 5, cx = (unit & 31) << 3;
      const float* p = xin + (size_t)(bm0 + row) * (Tdim * Idim) + (size_t)t * Idim + cx;
      float4 a = *(const float4*)p, b4 = *(const float4*)(p + 4);
      short8 v;
      v[0] = f2bf(a.x);  v[1] = f2bf(a.y);  v[2] = f2bf(a.z);  v[3] = f2bf(a.w);
      v[4] = f2bf(b4.x); v[5] = f2bf(b4.y); v[6] = f2bf(b4.z); v[7] = f2bf(b4.w);
      *(short8*)((char*)As + (((row * 2560) + (cx << 1)) ^ ((row & 15) << 4))) = v;
    }
    {
      const short* hbase = UhR + (size_t)(bm0 + row0) * Hdim + c8;
#pragma unroll
      for (int i = 0; i < 8; ++i) {
        const short* hp = hbase + (size_t)(4 * i) * Hdim;
        u64 lo = __hip_atomic_load((const u64*)hp, __ATOMIC_RELAXED,
                                   __HIP_MEMORY_SCOPE_AGENT);
        u64 hi = __hip_atomic_load((const u64*)(hp + 4), __ATOMIC_RELAXED,
                                   __HIP_MEMORY_SCOPE_AGENT);
        short4v vlo = __builtin_bit_cast(short4v, lo);
        short4v vhi = __builtin_bit_cast(short4v, hi);
        if (t > 0 && c8 == 0) {
          // oscillator state update on h cols 0,1 (transient, gate-input only)
          float x0 = bf2f(vlo[0]), x1 = bf2f(vlo[1]);
          vlo[0] = f2bf(x0 + 0.05f * (1.5f * x0 + (1.0f / 1.5f) * x1));
          vlo[1] = f2bf(x1 - 0.05f * 1.5f * x0);
        }
        int row = row0 + 4 * i;
        char* dst = (char*)As + (((row * 2560) + ((256 + c8) << 1)) ^ ((row & 15) << 4));
        *(short4v*)dst = vlo;
        *(short4v*)(dst + 8) = vhi;
      }
    }
    __syncthreads();

    // ---- MFMA: acc(32x32) += A[32 x 640-half] * W[640-half x 32] ----
    f32x16 acc;
#pragma unroll
    for (int i = 0; i < 16; ++i) acc[i] = 0.f;
#pragma unroll
    for (int ks = 0; ks < 40; ++ks) {
      short8 a = *(const short8*)((char*)As + ((rbase + ks * 32) ^ rxor));
      acc = __builtin_amdgcn_mfma_f32_32x32x16_bf16(a, Wreg[ks], acc, 0, 0, 0);
    }

    // ---- K-half partials to LDS ----
    {
      const int col = lane & 31, half = lane >> 5;
#pragma unroll
      for (int r = 0; r < 16; ++r) {
        int rl = (r & 3) + 8 * (r >> 2) + 4 * half;
        Gred[kh][rl][ntl * 32 + col] = acc[r];
      }
    }
    __syncthreads();

    // ---- fused LSTM epilogue: 2 adjacent cells per thread ----
    {
      float4 a0 = *(const float4*)&Gred[0][erow][8 * ep];
      float4 a1 = *(const float4*)&Gred[0][erow][8 * ep + 4];
      float4 d0 = *(const float4*)&Gred[1][erow][8 * ep];
      float4 d1 = *(const float4*)&Gred[1][erow][8 * ep + 4];
      float gx0 = a0.x + d0.x + bb0.x, gy0 = a0.y + d0.y + bb0.y;
      float gz0 = a0.z + d0.z + bb0.z, gw0 = a0.w + d0.w + bb0.w;
      float gx1 = a1.x + d1.x + bb1.x, gy1 = a1.y + d1.y + bb1.y;
      float gz1 = a1.z + d1.z + bb1.z, gw1 = a1.w + d1.w + bb1.w;
      float iv0 = 1.0f / (1.0f + __expf(-gx0));
      float fv0 = 1.0f / (1.0f + __expf(-gy0));
      float gg0 = 2.0f / (1.0f + __expf(-2.0f * gz0)) - 1.0f;
      float ov0 = 1.0f / (1.0f + __expf(-gw0));
      float iv1 = 1.0f / (1.0f + __expf(-gx1));
      float fv1 = 1.0f / (1.0f + __expf(-gy1));
      float gg1 = 2.0f / (1.0f + __expf(-2.0f * gz1)) - 1.0f;
      float ov1 = 1.0f / (1.0f + __expf(-gw1));
      int bm = bm0 + erow;
      int hu0 = ng * 32 + 2 * ep;
      size_t cidx = (size_t)bm * Hdim + hu0;
      float2 cold = *(const float2*)&c_state[cidx];
      float cn0 = fv0 * cold.x + iv0 * gg0;
      float cn1 = fv1 * cold.y + iv1 * gg1;
      *(float2*)&c_state[cidx] = make_float2(cn0, cn1);
      float hv0 = ov0 * (2.0f / (1.0f + __expf(-2.0f * cn0)) - 1.0f);
      float hv1 = ov1 * (2.0f / (1.0f + __expf(-2.0f * cn1)) - 1.0f);
      *(float2*)&out[(size_t)bm * (Tdim * Hdim) + (size_t)t * Hdim + hu0] =
          make_float2(hv0, hv1);
      unsigned hpk = (unsigned)(unsigned short)f2bf(hv0) |
                     ((unsigned)(unsigned short)f2bf(hv1) << 16);
      __hip_atomic_store((unsigned*)&UhW[cidx], hpk, __ATOMIC_RELAXED,
                         __HIP_MEMORY_SCOPE_AGENT);
      if (t == Tdim - 1) *(float2*)&hN[cidx] = make_float2(hv0, hv1);
    }

    if (t < Tdim - 1) {
      // ---- per-m-group barrier (32 blocks), monotonic flags, no fences ----
      asm volatile("s_waitcnt vmcnt(0)" ::: "memory");  // this wave's h at LLC
      __syncthreads();                                  // all waves drained
      if (wave == 0) {
        if (lane == 0)
          __hip_atomic_store(&flags[ng], (unsigned)(t + 1), __ATOMIC_RELAXED,
                             __HIP_MEMORY_SCOPE_AGENT);
        const unsigned tgt = (unsigned)(t + 1);
        for (;;) {
          unsigned v = __hip_atomic_load(&flags[lane & 31], __ATOMIC_RELAXED,
                                         __HIP_MEMORY_SCOPE_AGENT);
          if (__all((int)(v >= tgt))) break;
          __builtin_amdgcn_s_sleep(2);
        }
      }
      __syncthreads();
    }
  }
}

extern "C" void kernel_launch(void* const* d_in, const int* in_sizes, int n_in,
                              void* d_out, int out_size, void* d_ws, size_t ws_size,
                              hipStream_t stream) {
  const float* xin = (const float*)d_in[0];
  const float* h0  = (const float*)d_in[1];
  const float* c0  = (const float*)d_in[2];
  const float* Wx  = (const float*)d_in[3];
  const float* Wh  = (const float*)d_in[4];
  const float* b   = (const float*)d_in[5];
  float* out = (float*)d_out;

  // workspace layout (~11.6 MB): Wt | Uh0 | Uh1 | bp | bar
  char* ws = (char*)d_ws;
  short* Wt  = (short*)ws;                                   // 4096*1280*2 = 10485760
  short* Uh0 = (short*)(ws + 10485760);                      // 524288
  short* Uh1 = (short*)(ws + 10485760 + 524288);             // 524288
  float* bp  = (float*)(ws + 10485760 + 1048576);            // 16384
  unsigned* bar = (unsigned*)(ws + 10485760 + 1048576 + 16384);  // 1024 B

  float* hN      = out + (size_t)Bdim * Tdim * Hdim;
  float* c_state = hN + (size_t)Bdim * Hdim;   // cN region doubles as running c

  setup_wt_kernel<<<dim3(64, 20), 256, 0, stream>>>(Wx, Wh, Wt);
  setup_state_kernel<<<1042, 256, 0, stream>>>(h0, c0, b, Uh0, c_state, bp, bar);

  void* args[] = {(void*)&xin, (void*)&Wt, (void*)&bp, (void*)&Uh0, (void*)&Uh1,
                  (void*)&out, (void*)&c_state, (void*)&hN, (void*)&bar};
  hipLaunchCooperativeKernel((const void*)lstm_persistent, dim3(256), dim3(512),
                             args, 0, stream);
}